// Round 3
// baseline (924.505 us; speedup 1.0000x reference)
//
#include <hip/hip_runtime.h>
#include <hip/hip_bf16.h>
#include <stdint.h>

// ---------- types ----------
typedef __attribute__((ext_vector_type(8))) __bf16 bf16x8;
typedef __attribute__((ext_vector_type(8))) short short8v;
typedef __attribute__((ext_vector_type(4))) short short4v;
typedef __attribute__((ext_vector_type(4))) float f32x4;

__device__ __forceinline__ float bf2f(short u) {
  return __builtin_bit_cast(float, (uint32_t)((uint32_t)(uint16_t)u << 16));
}
__device__ __forceinline__ short f2bf(float f) {
  uint32_t x = __builtin_bit_cast(uint32_t, f);
  x += 0x7FFFu + ((x >> 16) & 1u);
  return (short)(x >> 16);
}
__device__ __forceinline__ f32x4 mfma16(short8v a, short8v b, f32x4 c) {
  return __builtin_amdgcn_mfma_f32_16x16x32_bf16(
      __builtin_bit_cast(bf16x8, a), __builtin_bit_cast(bf16x8, b), c, 0, 0, 0);
}
// swap lanes ll <-> ll^1 via DPP quad_perm [1,0,3,2] (VALU, no LDS traffic)
__device__ __forceinline__ float dpp_xor1(float x) {
  int i = __builtin_bit_cast(int, x);
  int r = __builtin_amdgcn_update_dpp(i, i, 0xB1, 0xF, 0xF, true);
  return __builtin_bit_cast(float, r);
}
// XOR-swizzled LDS address (shorts). stride S shorts, 16B-chunk swizzle.
// Conflict-free for MFMA A-frag reads AND row-major chunk writes.
__device__ __forceinline__ int swz256(int row, int col) {
  return row * 256 + (col ^ ((row & 7) << 3));
}
__device__ __forceinline__ int swz128(int row, int col) {
  return row * 128 + (col ^ ((row & 7) << 3));
}

// ---------- merged prepack: all 11 weights in ONE launch ----------
// dst layout per weight: [nt][kt][lane][8 bf16]; B[k=kt*32+(lane>>4)*8+j][n=nt*16+(lane&15)]
struct PPDesc { const float* src; short* dst; int Ks, Ns, KT, NT, tile_base; };
struct PPArgs { PPDesc d[11]; int n_desc; int total_tiles; };

__global__ void prepack_all(PPArgs args) {
  int idx = blockIdx.x * 256 + threadIdx.x;
  int tile = idx >> 6;
  if (tile >= args.total_tiles) return;
  int lane = idx & 63;
  int e = 0;
  while (e + 1 < args.n_desc && args.d[e + 1].tile_base <= tile) ++e;
  const PPDesc D = args.d[e];
  int t = tile - D.tile_base;
  int kt = t % D.KT, nt = t / D.KT;
  int n = nt * 16 + (lane & 15);
  int kbase = kt * 32 + ((lane >> 4) * 8);
  short8v o;
#pragma unroll
  for (int j = 0; j < 8; ++j) {
    int k = kbase + j;
    o[j] = f2bf((k < D.Ks && n < D.Ns) ? D.src[k * D.Ns + n] : 0.f);
  }
  *(short8v*)&D.dst[((size_t)t * 64 + lane) * 8] = o;
}

// ---------- qb[b,c] = qst[b] @ Wg1[200:211] + bg1 (32 batches/block) ----------
__global__ void qb_kernel(const float* __restrict__ qst, const float* __restrict__ Wg1,
                          const float* __restrict__ bg1, float* __restrict__ qb) {
  int c = threadIdx.x;
  int b0 = blockIdx.x * 32;
  float wcol[11];
#pragma unroll
  for (int k = 0; k < 11; ++k) wcol[k] = Wg1[(200 + k) * 256 + c];
  float bias = bg1[c];
#pragma unroll 1
  for (int bb = 0; bb < 32; ++bb) {
    int b = b0 + bb;
    float acc = bias;
#pragma unroll
    for (int k = 0; k < 11; ++k) acc += qst[b * 11 + k] * wcol[k];
    qb[b * 256 + c] = acc;
  }
}

// ---------- encoder: tabs[64 rows x 10] -> x -> u,v (bf16, [obj][256]) ----------
__launch_bounds__(256, 3)
__global__ void enc_kernel(const float* __restrict__ tabs,
    const float* __restrict__ bi1, const float* __restrict__ bi2, const float* __restrict__ bi3,
    const short* __restrict__ Wi1p, const short* __restrict__ Wi2p, const short* __restrict__ Wi3p,
    const short* __restrict__ Wap, const short* __restrict__ Wbp,
    short* __restrict__ u_g, short* __restrict__ v_g) {
  __shared__ __align__(16) short sIn[64 * 32];   // K padded 10->32
  __shared__ __align__(16) short sH1[64 * 256];  // swizzled; sX aliases this after L2
  __shared__ __align__(16) short sH2[64 * 128];  // swizzled
  short* sX = sH1;                               // reuse (stride 128, swizzled)
  const int tid = threadIdx.x;
  const int lane = tid & 63, w = tid >> 6, quad = lane >> 4, ll = lane & 15;
  const int xl = (ll & 7) << 3;
  const int obj0 = blockIdx.x * 64;

  for (int idx = tid; idx < 64 * 32; idx += 256) {
    int r = idx >> 5, k = idx & 31;
    float v = (k < 10) ? tabs[(obj0 + r) * 10 + k] : 0.f;
    sIn[idx] = f2bf(v);
  }
  __syncthreads();

  // L1: relu(in @ Wi1 + bi1)  K=32(pad), N=256
  {
    f32x4 acc[4][4] = {};
    short8v a[4];
#pragma unroll
    for (int mt = 0; mt < 4; ++mt)
      a[mt] = *(const short8v*)&sIn[(mt * 16 + ll) * 32 + quad * 8];
#pragma unroll
    for (int ni = 0; ni < 4; ++ni) {
      short8v b = *(const short8v*)&Wi1p[((w * 4 + ni) * 64 + lane) * 8];
#pragma unroll
      for (int mt = 0; mt < 4; ++mt) acc[mt][ni] = mfma16(a[mt], b, acc[mt][ni]);
    }
#pragma unroll
    for (int ni = 0; ni < 4; ++ni) {
      int col = (w * 4 + ni) * 16 + ll;
      float bias = bi1[col];
#pragma unroll
      for (int mt = 0; mt < 4; ++mt)
#pragma unroll
        for (int r = 0; r < 4; ++r) {
          int row = mt * 16 + quad * 4 + r;
          sH1[swz256(row, col)] = f2bf(fmaxf(acc[mt][ni][r] + bias, 0.f));
        }
    }
  }
  __syncthreads();

  // L2: relu(h1 @ Wi2 + bi2)  K=256, N=128
  {
    f32x4 acc[4][2] = {};
#pragma unroll 1
    for (int kt = 0; kt < 8; ++kt) {
      short8v b[2];
#pragma unroll
      for (int ni = 0; ni < 2; ++ni)
        b[ni] = *(const short8v*)&Wi2p[(((w * 2 + ni) * 8 + kt) * 64 + lane) * 8];
#pragma unroll
      for (int mt = 0; mt < 4; ++mt) {
        short8v a = *(const short8v*)&sH1[(mt * 16 + ll) * 256 + ((kt * 32 + quad * 8) ^ xl)];
#pragma unroll
        for (int ni = 0; ni < 2; ++ni) acc[mt][ni] = mfma16(a, b[ni], acc[mt][ni]);
      }
    }
    __syncthreads();   // sH1 reads done (sX will overwrite it after L3)
#pragma unroll
    for (int ni = 0; ni < 2; ++ni) {
      int col = (w * 2 + ni) * 16 + ll;
      float bias = bi2[col];
#pragma unroll
      for (int mt = 0; mt < 4; ++mt)
#pragma unroll
        for (int r = 0; r < 4; ++r) {
          int row = mt * 16 + quad * 4 + r;
          sH2[swz128(row, col)] = f2bf(fmaxf(acc[mt][ni][r] + bias, 0.f));
        }
    }
  }
  __syncthreads();

  // L3: x = h2 @ Wi3 + bi3 (NO relu)  K=128, N=128(pad, cols>=100 zero) -> sX (aliases sH1)
  {
    f32x4 acc[4][2] = {};
#pragma unroll 1
    for (int kt = 0; kt < 4; ++kt) {
      short8v b[2];
#pragma unroll
      for (int ni = 0; ni < 2; ++ni)
        b[ni] = *(const short8v*)&Wi3p[(((w * 2 + ni) * 4 + kt) * 64 + lane) * 8];
#pragma unroll
      for (int mt = 0; mt < 4; ++mt) {
        short8v a = *(const short8v*)&sH2[(mt * 16 + ll) * 128 + ((kt * 32 + quad * 8) ^ xl)];
#pragma unroll
        for (int ni = 0; ni < 2; ++ni) acc[mt][ni] = mfma16(a, b[ni], acc[mt][ni]);
      }
    }
#pragma unroll
    for (int ni = 0; ni < 2; ++ni) {
      int col = (w * 2 + ni) * 16 + ll;
      float bias = (col < 100) ? bi3[col] : 0.f;
#pragma unroll
      for (int mt = 0; mt < 4; ++mt)
#pragma unroll
        for (int r = 0; r < 4; ++r) {
          int row = mt * 16 + quad * 4 + r;
          float vv = (col < 100) ? (acc[mt][ni][r] + bias) : 0.f;
          sX[swz128(row, col)] = f2bf(vv);
        }
    }
  }
  __syncthreads();

  // L4: u = x @ Wa ; v = x @ Wb   K=128, N=256 each
#pragma unroll 1
  for (int pass = 0; pass < 2; ++pass) {
    const short* Wp = pass ? Wbp : Wap;
    short* outg = pass ? v_g : u_g;
    f32x4 acc[4][4] = {};
#pragma unroll 1
    for (int kt = 0; kt < 4; ++kt) {
      short8v b[4];
#pragma unroll
      for (int ni = 0; ni < 4; ++ni)
        b[ni] = *(const short8v*)&Wp[(((w * 4 + ni) * 4 + kt) * 64 + lane) * 8];
#pragma unroll
      for (int mt = 0; mt < 4; ++mt) {
        short8v a = *(const short8v*)&sX[(mt * 16 + ll) * 128 + ((kt * 32 + quad * 8) ^ xl)];
#pragma unroll
        for (int ni = 0; ni < 4; ++ni) acc[mt][ni] = mfma16(a, b[ni], acc[mt][ni]);
      }
    }
#pragma unroll
    for (int ni = 0; ni < 4; ++ni) {
      int col = (w * 4 + ni) * 16 + ll;
#pragma unroll
      for (int mt = 0; mt < 4; ++mt)
#pragma unroll
        for (int r = 0; r < 4; ++r)
          outg[(obj0 + mt * 16 + quad * 4 + r) * 256 + col] = f2bf(acc[mt][ni][r]);
    }
  }
}

// ---------- pair MLP: 2 batches/block, 72 rows (pad->80), fused g2..g4 + pool ----------
// sH XOR-swizzled (16B chunks): A-frag ds_read_b128 and chunk writes are bank-uniform.
__launch_bounds__(256, 3)
__global__ void pair_kernel(const short* __restrict__ u_g, const short* __restrict__ v_g,
    const float* __restrict__ qbp,
    const short* __restrict__ Wg2p, const short* __restrict__ Wg3p, const short* __restrict__ Wg4p,
    const float* __restrict__ bg2, const float* __restrict__ bg3, const float* __restrict__ bg4,
    float* __restrict__ g_g) {
  __shared__ __align__(16) short sH[80 * 256];   // 40,960 B, swizzled
  __shared__ float pool[2 * 256];                // 2 KB
  const int tid = threadIdx.x;
  const int lane = tid & 63, w = tid >> 6, quad = lane >> 4, ll = lane & 15;
  const int xl = (ll & 7) << 3;
  const int b0 = blockIdx.x * 2;

  for (int i = tid; i < 512; i += 256) pool[i] = 0.f;
  // zero pad rows 72..79 (any swizzle permutation of zeros is zeros)
  *(short8v*)&sH[72 * 256 + tid * 8] = short8v{0, 0, 0, 0, 0, 0, 0, 0};

  // h1 = relu(u[j] + v[i] + qb): one 16B chunk (8 cols of one row) per thread.
  // row = bb*36 + i*6 + j; 72 rows x 32 chunks = 2304 = 9 * 256.
  {
    short8v u_c, v_c; f32x4 qa_c, qc_c; int dst_c;
    auto addrs = [&](int vi, short8v& u8, short8v& v8, f32x4& qa, f32x4& qc, int& dst) {
      int row = vi >> 5, c8 = (vi & 31) * 8;
      int bb = row / 36, p = row - bb * 36;
      int i2 = p / 6, j2 = p - i2 * 6;
      u8 = *(const short8v*)&u_g[((b0 + bb) * 6 + j2) * 256 + c8];
      v8 = *(const short8v*)&v_g[((b0 + bb) * 6 + i2) * 256 + c8];
      qa = *(const f32x4*)&qbp[(b0 + bb) * 256 + c8];
      qc = *(const f32x4*)&qbp[(b0 + bb) * 256 + c8 + 4];
      dst = row * 256 + (c8 ^ ((row & 7) << 3));
    };
    addrs(tid, u_c, v_c, qa_c, qc_c, dst_c);
#pragma unroll 1
    for (int it = 0; it < 9; ++it) {
      short8v u_n = {}, v_n = {}; f32x4 qa_n = {}, qc_n = {}; int dst_n = 0;
      if (it < 8) addrs((it + 1) * 256 + tid, u_n, v_n, qa_n, qc_n, dst_n);
      short8v o;
#pragma unroll
      for (int e = 0; e < 4; ++e)
        o[e] = f2bf(fmaxf(bf2f(u_c[e]) + bf2f(v_c[e]) + qa_c[e], 0.f));
#pragma unroll
      for (int e = 0; e < 4; ++e)
        o[4 + e] = f2bf(fmaxf(bf2f(u_c[4 + e]) + bf2f(v_c[4 + e]) + qc_c[e], 0.f));
      *(short8v*)&sH[dst_c] = o;
      u_c = u_n; v_c = v_n; qa_c = qa_n; qc_c = qc_n; dst_c = dst_n;
    }
  }
  __syncthreads();

#pragma unroll 1
  for (int L = 0; L < 3; ++L) {
    const short* __restrict__ Wp = (L == 0) ? Wg2p : (L == 1) ? Wg3p : Wg4p;
    const float* __restrict__ bp = (L == 0) ? bg2 : (L == 1) ? bg3 : bg4;
    f32x4 acc[5][4] = {};
    short8v bA[4], bB[4];
#pragma unroll
    for (int ni = 0; ni < 4; ++ni)
      bA[ni] = *(const short8v*)&Wp[(((w * 4 + ni) * 8 + 0) * 64 + lane) * 8];
#pragma unroll 1
    for (int kt = 0; kt < 8; kt += 2) {
#pragma unroll
      for (int ni = 0; ni < 4; ++ni)
        bB[ni] = *(const short8v*)&Wp[(((w * 4 + ni) * 8 + kt + 1) * 64 + lane) * 8];
      {
        short8v a[5];
#pragma unroll
        for (int mt = 0; mt < 5; ++mt)
          a[mt] = *(const short8v*)&sH[(mt * 16 + ll) * 256 + ((kt * 32 + quad * 8) ^ xl)];
#pragma unroll
        for (int mt = 0; mt < 5; ++mt)
#pragma unroll
          for (int ni = 0; ni < 4; ++ni) acc[mt][ni] = mfma16(a[mt], bA[ni], acc[mt][ni]);
      }
      if (kt + 2 < 8) {
#pragma unroll
        for (int ni = 0; ni < 4; ++ni)
          bA[ni] = *(const short8v*)&Wp[(((w * 4 + ni) * 8 + kt + 2) * 64 + lane) * 8];
      }
      {
        short8v a[5];
#pragma unroll
        for (int mt = 0; mt < 5; ++mt)
          a[mt] = *(const short8v*)&sH[(mt * 16 + ll) * 256 + (((kt + 1) * 32 + quad * 8) ^ xl)];
#pragma unroll
        for (int mt = 0; mt < 5; ++mt)
#pragma unroll
          for (int ni = 0; ni < 4; ++ni) acc[mt][ni] = mfma16(a[mt], bB[ni], acc[mt][ni]);
      }
    }
    __syncthreads();  // all reads of sH done before in-place overwrite
    if (L < 2) {
      // Epilogue: DPP lane-pair swap -> b32 writes (2 cols x 1 row per store).
#pragma unroll
      for (int ni = 0; ni < 4; ++ni) {
        int col = (w * 4 + ni) * 16 + ll;
        float bias = bp[col];
#pragma unroll
        for (int mt = 0; mt < 5; ++mt) {
          float h0 = fmaxf(acc[mt][ni][0] + bias, 0.f);
          float h1 = fmaxf(acc[mt][ni][1] + bias, 0.f);
          float h2 = fmaxf(acc[mt][ni][2] + bias, 0.f);
          float h3 = fmaxf(acc[mt][ni][3] + bias, 0.f);
          float p0 = dpp_xor1(h0), p1 = dpp_xor1(h1);
          float p2 = dpp_xor1(h2), p3 = dpp_xor1(h3);
          int rb = mt * 16 + quad * 4;
          if ((ll & 1) == 0) {
            int cp = col;
            uint32_t d0 = (uint32_t)(uint16_t)f2bf(h0) | ((uint32_t)(uint16_t)f2bf(p0) << 16);
            uint32_t d1 = (uint32_t)(uint16_t)f2bf(h1) | ((uint32_t)(uint16_t)f2bf(p1) << 16);
            *(uint32_t*)&sH[swz256(rb + 0, cp)] = d0;
            *(uint32_t*)&sH[swz256(rb + 1, cp)] = d1;
          } else {
            int cp = col - 1;
            uint32_t d2 = (uint32_t)(uint16_t)f2bf(p2) | ((uint32_t)(uint16_t)f2bf(h2) << 16);
            uint32_t d3 = (uint32_t)(uint16_t)f2bf(p3) | ((uint32_t)(uint16_t)f2bf(h3) << 16);
            *(uint32_t*)&sH[swz256(rb + 2, cp)] = d2;
            *(uint32_t*)&sH[swz256(rb + 3, cp)] = d3;
          }
        }
      }
      __syncthreads();
    } else {
      // g4: relu + sum-pool. 4-row groups never cross the row-36 batch boundary.
#pragma unroll
      for (int ni = 0; ni < 4; ++ni) {
        int col = (w * 4 + ni) * 16 + ll;
        float bias = bp[col];
#pragma unroll
        for (int mt = 0; mt < 5; ++mt) {
          int rbase = mt * 16 + quad * 4;
          if (rbase < 72) {
            int bb = rbase / 36;
            float s = 0.f;
#pragma unroll
            for (int r = 0; r < 4; ++r) s += fmaxf(acc[mt][ni][r] + bias, 0.f);
            atomicAdd(&pool[bb * 256 + col], s);
          }
        }
      }
      __syncthreads();
      for (int t = tid; t < 512; t += 256)
        g_g[(b0 + (t >> 8)) * 256 + (t & 255)] = pool[t];
    }
  }
}

// ---------- head helper: 64x256 @ 256x256 + bias + relu, LDS->LDS (swizzled) ----------
__device__ __forceinline__ void gemm64x256(const short* sInp, short* sOut,
    const short* __restrict__ Wp, const float* __restrict__ bias,
    int w, int lane, int quad, int ll, int xl) {
  f32x4 acc[4][4] = {};
#pragma unroll 1
  for (int kt = 0; kt < 8; ++kt) {
    short8v b[4];
#pragma unroll
    for (int ni = 0; ni < 4; ++ni)
      b[ni] = *(const short8v*)&Wp[(((w * 4 + ni) * 8 + kt) * 64 + lane) * 8];
#pragma unroll
    for (int mt = 0; mt < 4; ++mt) {
      short8v a = *(const short8v*)&sInp[(mt * 16 + ll) * 256 + ((kt * 32 + quad * 8) ^ xl)];
#pragma unroll
      for (int ni = 0; ni < 4; ++ni) acc[mt][ni] = mfma16(a, b[ni], acc[mt][ni]);
    }
  }
#pragma unroll
  for (int ni = 0; ni < 4; ++ni) {
    int col = (w * 4 + ni) * 16 + ll;
    float bv = bias[col];
#pragma unroll
    for (int mt = 0; mt < 4; ++mt)
#pragma unroll
      for (int r = 0; r < 4; ++r) {
        int row = mt * 16 + quad * 4 + r;
        sOut[swz256(row, col)] = f2bf(fmaxf(acc[mt][ni][r] + bv, 0.f));
      }
  }
}

// ---------- head: g -> f -> o -> logits -> log_softmax ----------
__launch_bounds__(256, 2)
__global__ void head_kernel(const float* __restrict__ g_g,
    const short* __restrict__ Wfp, const float* __restrict__ bf_,
    const short* __restrict__ Wo1p, const float* __restrict__ bo1,
    const short* __restrict__ Wo2p, const float* __restrict__ bo2,
    float* __restrict__ outp) {
  __shared__ __align__(16) short sA[64 * 256];
  __shared__ __align__(16) short sB[64 * 256];
  __shared__ float sL[64 * 16];
  const int tid = threadIdx.x;
  const int lane = tid & 63, w = tid >> 6, quad = lane >> 4, ll = lane & 15;
  const int xl = (ll & 7) << 3;
  const int b0 = blockIdx.x * 64;

#pragma unroll 1
  for (int it = 0; it < 16; ++it) {
    int vi = it * 256 + tid;
    int row = vi >> 6, c4 = (vi & 63) * 4;
    f32x4 gv = *(const f32x4*)&g_g[(b0 + row) * 256 + c4];
    short4v o;
#pragma unroll
    for (int e = 0; e < 4; ++e) o[e] = f2bf(gv[e]);
    *(short4v*)&sA[row * 256 + (c4 ^ ((row & 7) << 3))] = o;
  }
  __syncthreads();
  gemm64x256(sA, sB, Wfp, bf_, w, lane, quad, ll, xl);
  __syncthreads();
  gemm64x256(sB, sA, Wo1p, bo1, w, lane, quad, ll, xl);
  __syncthreads();
  {
    f32x4 acc = {};
#pragma unroll 1
    for (int kt = 0; kt < 8; ++kt) {
      short8v b = *(const short8v*)&Wo2p[(kt * 64 + lane) * 8];
      short8v a = *(const short8v*)&sA[(w * 16 + ll) * 256 + ((kt * 32 + quad * 8) ^ xl)];
      acc = mfma16(a, b, acc);
    }
#pragma unroll
    for (int r = 0; r < 4; ++r) {
      int row = w * 16 + quad * 4 + r;
      sL[row * 16 + ll] = acc[r] + ((ll < 10) ? bo2[ll] : 0.f);
    }
  }
  __syncthreads();
  if (tid < 64) {
    float m = -1e30f;
#pragma unroll
    for (int c = 0; c < 10; ++c) m = fmaxf(m, sL[tid * 16 + c]);
    float s = 0.f;
#pragma unroll
    for (int c = 0; c < 10; ++c) s += expf(sL[tid * 16 + c] - m);
    float ls = logf(s) + m;
#pragma unroll
    for (int c = 0; c < 10; ++c) outp[(b0 + tid) * 10 + c] = sL[tid * 16 + c] - ls;
  }
}

extern "C" void kernel_launch(void* const* d_in, const int* in_sizes, int n_in,
                              void* d_out, int out_size, void* d_ws, size_t ws_size,
                              hipStream_t stream) {
  const float* tabs = (const float*)d_in[0];
  const float* qst  = (const float*)d_in[1];
  const float* Wi1 = (const float*)d_in[2];  const float* bi1 = (const float*)d_in[3];
  const float* Wi2 = (const float*)d_in[4];  const float* bi2 = (const float*)d_in[5];
  const float* Wi3 = (const float*)d_in[6];  const float* bi3 = (const float*)d_in[7];
  const float* Wg1 = (const float*)d_in[8];  const float* bg1 = (const float*)d_in[9];
  const float* Wg2 = (const float*)d_in[10]; const float* bg2 = (const float*)d_in[11];
  const float* Wg3 = (const float*)d_in[12]; const float* bg3 = (const float*)d_in[13];
  const float* Wg4 = (const float*)d_in[14]; const float* bg4 = (const float*)d_in[15];
  const float* Wf  = (const float*)d_in[16]; const float* bf_ = (const float*)d_in[17];
  const float* Wo1 = (const float*)d_in[18]; const float* bo1 = (const float*)d_in[19];
  const float* Wo2 = (const float*)d_in[20]; const float* bo2 = (const float*)d_in[21];
  float* outp = (float*)d_out;
  (void)in_sizes; (void)n_in; (void)out_size; (void)ws_size;

  char* ws = (char*)d_ws;
  size_t off = 0;
  auto alloc = [&](size_t bytes) { void* p = ws + off; off += (bytes + 255) & ~(size_t)255; return p; };
  const size_t BN = 16384ull * 6;
  short* u_g = (short*)alloc(BN * 256 * 2);
  short* v_g = (short*)alloc(BN * 256 * 2);
  float* qb  = (float*)alloc(16384ull * 256 * 4);
  float* g_g = (float*)alloc(16384ull * 256 * 4);
  short* Wi1p = (short*)alloc(16 * 1 * 64 * 8 * 2);
  short* Wi2p = (short*)alloc(8 * 8 * 64 * 8 * 2);
  short* Wi3p = (short*)alloc(8 * 4 * 64 * 8 * 2);
  short* Wap  = (short*)alloc(16 * 4 * 64 * 8 * 2);
  short* Wbp  = (short*)alloc(16 * 4 * 64 * 8 * 2);
  short* Wg2p = (short*)alloc(16 * 8 * 64 * 8 * 2);
  short* Wg3p = (short*)alloc(16 * 8 * 64 * 8 * 2);
  short* Wg4p = (short*)alloc(16 * 8 * 64 * 8 * 2);
  short* Wfp  = (short*)alloc(16 * 8 * 64 * 8 * 2);
  short* Wo1p = (short*)alloc(16 * 8 * 64 * 8 * 2);
  short* Wo2p = (short*)alloc(1 * 8 * 64 * 8 * 2);

  PPArgs pa;
  int tb = 0, nd = 0;
  auto add = [&](const float* src, short* dst, int Ks, int Ns, int KT, int NT) {
    pa.d[nd++] = PPDesc{src, dst, Ks, Ns, KT, NT, tb};
    tb += KT * NT;
  };
  add(Wi1, Wi1p, 10, 256, 1, 16);
  add(Wi2, Wi2p, 256, 128, 8, 8);
  add(Wi3, Wi3p, 128, 100, 4, 8);
  add(Wg1,             Wap, 100, 256, 4, 16);
  add(Wg1 + 100 * 256, Wbp, 100, 256, 4, 16);
  add(Wg2, Wg2p, 256, 256, 8, 16);
  add(Wg3, Wg3p, 256, 256, 8, 16);
  add(Wg4, Wg4p, 256, 256, 8, 16);
  add(Wf,  Wfp,  256, 256, 8, 16);
  add(Wo1, Wo1p, 256, 256, 8, 16);
  add(Wo2, Wo2p, 256, 10, 8, 1);
  pa.n_desc = nd;
  pa.total_tiles = tb;
  prepack_all<<<(tb * 64 + 255) / 256, 256, 0, stream>>>(pa);

  qb_kernel<<<512, 256, 0, stream>>>(qst, Wg1, bg1, qb);
  enc_kernel<<<1536, 256, 0, stream>>>(tabs, bi1, bi2, bi3, Wi1p, Wi2p, Wi3p, Wap, Wbp, u_g, v_g);
  pair_kernel<<<8192, 256, 0, stream>>>(u_g, v_g, qb, Wg2p, Wg3p, Wg4p, bg2, bg3, bg4, g_g);
  head_kernel<<<256, 256, 0, stream>>>(g_g, Wfp, bf_, Wo1p, bo1, Wo2p, bo2, outp);
}

// Round 4
// 553.086 us; speedup vs baseline: 1.6715x; 1.6715x over previous
//
#include <hip/hip_runtime.h>
#include <hip/hip_bf16.h>
#include <stdint.h>

// ---------- types ----------
typedef __attribute__((ext_vector_type(8))) __bf16 bf16x8;
typedef __attribute__((ext_vector_type(8))) short short8v;
typedef __attribute__((ext_vector_type(4))) short short4v;
typedef __attribute__((ext_vector_type(4))) float f32x4;

__device__ __forceinline__ float bf2f(short u) {
  return __builtin_bit_cast(float, (uint32_t)((uint32_t)(uint16_t)u << 16));
}
__device__ __forceinline__ short f2bf(float f) {
  uint32_t x = __builtin_bit_cast(uint32_t, f);
  x += 0x7FFFu + ((x >> 16) & 1u);
  return (short)(x >> 16);
}
__device__ __forceinline__ f32x4 mfma16(short8v a, short8v b, f32x4 c) {
  return __builtin_amdgcn_mfma_f32_16x16x32_bf16(
      __builtin_bit_cast(bf16x8, a), __builtin_bit_cast(bf16x8, b), c, 0, 0, 0);
}
// XOR-swizzled LDS address (shorts), stride 256/128 shorts, 16B-chunk swizzle.
__device__ __forceinline__ int swz256(int row, int col) {
  return row * 256 + (col ^ ((row & 7) << 3));
}
__device__ __forceinline__ int swz128(int row, int col) {
  return row * 128 + (col ^ ((row & 7) << 3));
}

// ---------- merged prepack: all 11 weights in ONE launch ----------
// dst layout per weight: [nt][kt][lane][8 bf16]; B[k=kt*32+(lane>>4)*8+j][n=nt*16+(lane&15)]
struct PPDesc { const float* src; short* dst; int Ks, Ns, KT, NT, tile_base; };
struct PPArgs { PPDesc d[11]; int n_desc; int total_tiles; };

__global__ void prepack_all(PPArgs args) {
  int idx = blockIdx.x * 256 + threadIdx.x;
  int tile = idx >> 6;
  if (tile >= args.total_tiles) return;
  int lane = idx & 63;
  int e = 0;
  while (e + 1 < args.n_desc && args.d[e + 1].tile_base <= tile) ++e;
  const PPDesc D = args.d[e];
  int t = tile - D.tile_base;
  int kt = t % D.KT, nt = t / D.KT;
  int n = nt * 16 + (lane & 15);
  int kbase = kt * 32 + ((lane >> 4) * 8);
  short8v o;
#pragma unroll
  for (int j = 0; j < 8; ++j) {
    int k = kbase + j;
    o[j] = f2bf((k < D.Ks && n < D.Ns) ? D.src[k * D.Ns + n] : 0.f);
  }
  *(short8v*)&D.dst[((size_t)t * 64 + lane) * 8] = o;
}

// ---------- qb[b,c] = qst[b] @ Wg1[200:211] + bg1 (32 batches/block) ----------
__global__ void qb_kernel(const float* __restrict__ qst, const float* __restrict__ Wg1,
                          const float* __restrict__ bg1, float* __restrict__ qb) {
  int c = threadIdx.x;
  int b0 = blockIdx.x * 32;
  float wcol[11];
#pragma unroll
  for (int k = 0; k < 11; ++k) wcol[k] = Wg1[(200 + k) * 256 + c];
  float bias = bg1[c];
#pragma unroll 1
  for (int bb = 0; bb < 32; ++bb) {
    int b = b0 + bb;
    float acc = bias;
#pragma unroll
    for (int k = 0; k < 11; ++k) acc += qst[b * 11 + k] * wcol[k];
    qb[b * 256 + c] = acc;
  }
}

// ---------- encoder: tabs[64 rows x 10] -> x -> u,v (bf16, [obj][256]) ----------
// Unified-file budget @3 blocks/CU: acc 64 AGPR + ~85 VGPR = ~150 <= 170, no spill.
__launch_bounds__(256, 3)
__global__ void enc_kernel(const float* __restrict__ tabs,
    const float* __restrict__ bi1, const float* __restrict__ bi2, const float* __restrict__ bi3,
    const short* __restrict__ Wi1p, const short* __restrict__ Wi2p, const short* __restrict__ Wi3p,
    const short* __restrict__ Wap, const short* __restrict__ Wbp,
    short* __restrict__ u_g, short* __restrict__ v_g) {
  __shared__ __align__(16) short sIn[64 * 32];   // K padded 10->32
  __shared__ __align__(16) short sH1[64 * 256];  // swizzled; sX aliases this after L2
  __shared__ __align__(16) short sH2[64 * 128];  // swizzled
  short* sX = sH1;                               // reuse (stride 128, swizzled)
  const int tid = threadIdx.x;
  const int lane = tid & 63, w = tid >> 6, quad = lane >> 4, ll = lane & 15;
  const int xl = (ll & 7) << 3;
  const int obj0 = blockIdx.x * 64;

  for (int idx = tid; idx < 64 * 32; idx += 256) {
    int r = idx >> 5, k = idx & 31;
    float v = (k < 10) ? tabs[(obj0 + r) * 10 + k] : 0.f;
    sIn[idx] = f2bf(v);
  }
  __syncthreads();

  // L1: relu(in @ Wi1 + bi1)  K=32(pad), N=256
  {
    f32x4 acc[4][4] = {};
    short8v a[4];
#pragma unroll
    for (int mt = 0; mt < 4; ++mt)
      a[mt] = *(const short8v*)&sIn[(mt * 16 + ll) * 32 + quad * 8];
#pragma unroll
    for (int ni = 0; ni < 4; ++ni) {
      short8v b = *(const short8v*)&Wi1p[((w * 4 + ni) * 64 + lane) * 8];
#pragma unroll
      for (int mt = 0; mt < 4; ++mt) acc[mt][ni] = mfma16(a[mt], b, acc[mt][ni]);
    }
#pragma unroll
    for (int ni = 0; ni < 4; ++ni) {
      int col = (w * 4 + ni) * 16 + ll;
      float bias = bi1[col];
#pragma unroll
      for (int mt = 0; mt < 4; ++mt)
#pragma unroll
        for (int r = 0; r < 4; ++r) {
          int row = mt * 16 + quad * 4 + r;
          sH1[swz256(row, col)] = f2bf(fmaxf(acc[mt][ni][r] + bias, 0.f));
        }
    }
  }
  __syncthreads();

  // L2: relu(h1 @ Wi2 + bi2)  K=256, N=128
  {
    f32x4 acc[4][2] = {};
#pragma unroll 1
    for (int kt = 0; kt < 8; ++kt) {
      short8v b[2];
#pragma unroll
      for (int ni = 0; ni < 2; ++ni)
        b[ni] = *(const short8v*)&Wi2p[(((w * 2 + ni) * 8 + kt) * 64 + lane) * 8];
#pragma unroll
      for (int mt = 0; mt < 4; ++mt) {
        short8v a = *(const short8v*)&sH1[(mt * 16 + ll) * 256 + ((kt * 32 + quad * 8) ^ xl)];
#pragma unroll
        for (int ni = 0; ni < 2; ++ni) acc[mt][ni] = mfma16(a, b[ni], acc[mt][ni]);
      }
    }
    __syncthreads();   // sH1 reads done (sX will overwrite it after L3)
#pragma unroll
    for (int ni = 0; ni < 2; ++ni) {
      int col = (w * 2 + ni) * 16 + ll;
      float bias = bi2[col];
#pragma unroll
      for (int mt = 0; mt < 4; ++mt)
#pragma unroll
        for (int r = 0; r < 4; ++r) {
          int row = mt * 16 + quad * 4 + r;
          sH2[swz128(row, col)] = f2bf(fmaxf(acc[mt][ni][r] + bias, 0.f));
        }
    }
  }
  __syncthreads();

  // L3: x = h2 @ Wi3 + bi3 (NO relu)  K=128, N=128(pad, cols>=100 zero) -> sX (aliases sH1)
  {
    f32x4 acc[4][2] = {};
#pragma unroll 1
    for (int kt = 0; kt < 4; ++kt) {
      short8v b[2];
#pragma unroll
      for (int ni = 0; ni < 2; ++ni)
        b[ni] = *(const short8v*)&Wi3p[(((w * 2 + ni) * 4 + kt) * 64 + lane) * 8];
#pragma unroll
      for (int mt = 0; mt < 4; ++mt) {
        short8v a = *(const short8v*)&sH2[(mt * 16 + ll) * 128 + ((kt * 32 + quad * 8) ^ xl)];
#pragma unroll
        for (int ni = 0; ni < 2; ++ni) acc[mt][ni] = mfma16(a, b[ni], acc[mt][ni]);
      }
    }
#pragma unroll
    for (int ni = 0; ni < 2; ++ni) {
      int col = (w * 2 + ni) * 16 + ll;
      float bias = (col < 100) ? bi3[col] : 0.f;
#pragma unroll
      for (int mt = 0; mt < 4; ++mt)
#pragma unroll
        for (int r = 0; r < 4; ++r) {
          int row = mt * 16 + quad * 4 + r;
          float vv = (col < 100) ? (acc[mt][ni][r] + bias) : 0.f;
          sX[swz128(row, col)] = f2bf(vv);
        }
    }
  }
  __syncthreads();

  // L4: u = x @ Wa ; v = x @ Wb   K=128, N=256 each
#pragma unroll 1
  for (int pass = 0; pass < 2; ++pass) {
    const short* Wp = pass ? Wbp : Wap;
    short* outg = pass ? v_g : u_g;
    f32x4 acc[4][4] = {};
#pragma unroll 1
    for (int kt = 0; kt < 4; ++kt) {
      short8v b[4];
#pragma unroll
      for (int ni = 0; ni < 4; ++ni)
        b[ni] = *(const short8v*)&Wp[(((w * 4 + ni) * 4 + kt) * 64 + lane) * 8];
#pragma unroll
      for (int mt = 0; mt < 4; ++mt) {
        short8v a = *(const short8v*)&sX[(mt * 16 + ll) * 128 + ((kt * 32 + quad * 8) ^ xl)];
#pragma unroll
        for (int ni = 0; ni < 4; ++ni) acc[mt][ni] = mfma16(a, b[ni], acc[mt][ni]);
      }
    }
#pragma unroll
    for (int ni = 0; ni < 4; ++ni) {
      int col = (w * 4 + ni) * 16 + ll;
#pragma unroll
      for (int mt = 0; mt < 4; ++mt)
#pragma unroll
        for (int r = 0; r < 4; ++r)
          outg[(obj0 + mt * 16 + quad * 4 + r) * 256 + col] = f2bf(acc[mt][ni][r]);
    }
  }
}

// ---------- pair MLP: 512 threads (8 waves), 2 batches/block, 72 rows (pad->80) ----------
// Each wave owns 32 output cols: acc[5][2]=40 AGPR + ~50 VGPR (unified budget ~170 @ 24
// waves/CU) -> no spill. Pool is wave-private in cols -> shfl reduce, NO atomics.
__launch_bounds__(512, 6)
__global__ void pair_kernel(const short* __restrict__ u_g, const short* __restrict__ v_g,
    const float* __restrict__ qbp,
    const short* __restrict__ Wg2p, const short* __restrict__ Wg3p, const short* __restrict__ Wg4p,
    const float* __restrict__ bg2, const float* __restrict__ bg3, const float* __restrict__ bg4,
    float* __restrict__ g_g) {
  __shared__ __align__(16) short sH[80 * 256];   // 40,960 B, swizzled
  __shared__ float pool[2 * 256];                // 2 KB
  const int tid = threadIdx.x;
  const int lane = tid & 63, w = tid >> 6, quad = lane >> 4, ll = lane & 15;
  const int xl = (ll & 7) << 3;
  const int b0 = blockIdx.x * 2;

  // zero pad rows 72..79 (2048 shorts)
  if (tid < 256) *(short8v*)&sH[72 * 256 + tid * 8] = short8v{0, 0, 0, 0, 0, 0, 0, 0};

  // h1 = relu(u[j] + v[i] + qb): one 16B chunk (8 cols of one row) per thread.
  // row = bb*36 + i*6 + j; 72 rows x 32 chunks = 2304 chunks.
#pragma unroll 1
  for (int it = 0; it < 5; ++it) {
    int vi = it * 512 + tid;
    if (vi < 2304) {
      int row = vi >> 5, c8 = (vi & 31) * 8;
      int bb = row / 36, p = row - bb * 36;
      int i2 = p / 6, j2 = p - i2 * 6;
      short8v u8 = *(const short8v*)&u_g[((b0 + bb) * 6 + j2) * 256 + c8];
      short8v v8 = *(const short8v*)&v_g[((b0 + bb) * 6 + i2) * 256 + c8];
      f32x4 qa = *(const f32x4*)&qbp[(b0 + bb) * 256 + c8];
      f32x4 qc = *(const f32x4*)&qbp[(b0 + bb) * 256 + c8 + 4];
      short8v o;
#pragma unroll
      for (int e = 0; e < 4; ++e)
        o[e] = f2bf(fmaxf(bf2f(u8[e]) + bf2f(v8[e]) + qa[e], 0.f));
#pragma unroll
      for (int e = 0; e < 4; ++e)
        o[4 + e] = f2bf(fmaxf(bf2f(u8[4 + e]) + bf2f(v8[4 + e]) + qc[e], 0.f));
      *(short8v*)&sH[row * 256 + (c8 ^ ((row & 7) << 3))] = o;
    }
  }
  __syncthreads();

#pragma unroll 1
  for (int L = 0; L < 3; ++L) {
    const short* __restrict__ Wp = (L == 0) ? Wg2p : (L == 1) ? Wg3p : Wg4p;
    const float* __restrict__ bp = (L == 0) ? bg2 : (L == 1) ? bg3 : bg4;
    f32x4 acc[5][2] = {};
#pragma unroll 1
    for (int kt = 0; kt < 8; ++kt) {
      short8v b[2];
#pragma unroll
      for (int ni = 0; ni < 2; ++ni)
        b[ni] = *(const short8v*)&Wp[(((w * 2 + ni) * 8 + kt) * 64 + lane) * 8];
#pragma unroll
      for (int mt = 0; mt < 5; ++mt) {
        short8v a = *(const short8v*)&sH[(mt * 16 + ll) * 256 + ((kt * 32 + quad * 8) ^ xl)];
#pragma unroll
        for (int ni = 0; ni < 2; ++ni) acc[mt][ni] = mfma16(a, b[ni], acc[mt][ni]);
      }
    }
    __syncthreads();  // all reads of sH done before in-place overwrite
    if (L < 2) {
#pragma unroll
      for (int ni = 0; ni < 2; ++ni) {
        int col = (w * 2 + ni) * 16 + ll;
        float bias = bp[col];
#pragma unroll
        for (int mt = 0; mt < 5; ++mt)
#pragma unroll
          for (int r = 0; r < 4; ++r) {
            int row = mt * 16 + quad * 4 + r;
            sH[swz256(row, col)] = f2bf(fmaxf(acc[mt][ni][r] + bias, 0.f));
          }
      }
      __syncthreads();
    } else {
      // g4: relu + sum-pool, atomic-free. Lane accumulates its rows per batch,
      // cross-quad shfl reduce, quad 0 stores (cols are wave-private).
#pragma unroll
      for (int ni = 0; ni < 2; ++ni) {
        int col = (w * 2 + ni) * 16 + ll;
        float bias = bp[col];
        float s0 = 0.f, s1 = 0.f;
#pragma unroll
        for (int mt = 0; mt < 5; ++mt) {
          int rbase = mt * 16 + quad * 4;
          float t = 0.f;
#pragma unroll
          for (int r = 0; r < 4; ++r) t += fmaxf(acc[mt][ni][r] + bias, 0.f);
          if (rbase < 36) s0 += t;
          else if (rbase < 72) s1 += t;
        }
        s0 += __shfl_xor(s0, 16, 64); s0 += __shfl_xor(s0, 32, 64);
        s1 += __shfl_xor(s1, 16, 64); s1 += __shfl_xor(s1, 32, 64);
        if (quad == 0) { pool[col] = s0; pool[256 + col] = s1; }
      }
      __syncthreads();
      {
        int t = tid;  // 512 threads cover 2x256 exactly
        g_g[(b0 + (t >> 8)) * 256 + (t & 255)] = pool[t];
      }
    }
  }
}

// ---------- head helper: 64x256 @ 256x256 + bias + relu, LDS->LDS (swizzled) ----------
__device__ __forceinline__ void gemm64x256(const short* sInp, short* sOut,
    const short* __restrict__ Wp, const float* __restrict__ bias,
    int w, int lane, int quad, int ll, int xl) {
  f32x4 acc[4][4] = {};
#pragma unroll 1
  for (int kt = 0; kt < 8; ++kt) {
    short8v b[4];
#pragma unroll
    for (int ni = 0; ni < 4; ++ni)
      b[ni] = *(const short8v*)&Wp[(((w * 4 + ni) * 8 + kt) * 64 + lane) * 8];
#pragma unroll
    for (int mt = 0; mt < 4; ++mt) {
      short8v a = *(const short8v*)&sInp[(mt * 16 + ll) * 256 + ((kt * 32 + quad * 8) ^ xl)];
#pragma unroll
      for (int ni = 0; ni < 4; ++ni) acc[mt][ni] = mfma16(a, b[ni], acc[mt][ni]);
    }
  }
#pragma unroll
  for (int ni = 0; ni < 4; ++ni) {
    int col = (w * 4 + ni) * 16 + ll;
    float bv = bias[col];
#pragma unroll
    for (int mt = 0; mt < 4; ++mt)
#pragma unroll
      for (int r = 0; r < 4; ++r) {
        int row = mt * 16 + quad * 4 + r;
        sOut[swz256(row, col)] = f2bf(fmaxf(acc[mt][ni][r] + bv, 0.f));
      }
  }
}

// ---------- head: g -> f -> o -> logits -> log_softmax ----------
__launch_bounds__(256, 2)
__global__ void head_kernel(const float* __restrict__ g_g,
    const short* __restrict__ Wfp, const float* __restrict__ bf_,
    const short* __restrict__ Wo1p, const float* __restrict__ bo1,
    const short* __restrict__ Wo2p, const float* __restrict__ bo2,
    float* __restrict__ outp) {
  __shared__ __align__(16) short sA[64 * 256];
  __shared__ __align__(16) short sB[64 * 256];
  __shared__ float sL[64 * 16];
  const int tid = threadIdx.x;
  const int lane = tid & 63, w = tid >> 6, quad = lane >> 4, ll = lane & 15;
  const int xl = (ll & 7) << 3;
  const int b0 = blockIdx.x * 64;

#pragma unroll 1
  for (int it = 0; it < 16; ++it) {
    int vi = it * 256 + tid;
    int row = vi >> 6, c4 = (vi & 63) * 4;
    f32x4 gv = *(const f32x4*)&g_g[(b0 + row) * 256 + c4];
    short4v o;
#pragma unroll
    for (int e = 0; e < 4; ++e) o[e] = f2bf(gv[e]);
    *(short4v*)&sA[row * 256 + (c4 ^ ((row & 7) << 3))] = o;
  }
  __syncthreads();
  gemm64x256(sA, sB, Wfp, bf_, w, lane, quad, ll, xl);
  __syncthreads();
  gemm64x256(sB, sA, Wo1p, bo1, w, lane, quad, ll, xl);
  __syncthreads();
  {
    f32x4 acc = {};
#pragma unroll 1
    for (int kt = 0; kt < 8; ++kt) {
      short8v b = *(const short8v*)&Wo2p[(kt * 64 + lane) * 8];
      short8v a = *(const short8v*)&sA[(w * 16 + ll) * 256 + ((kt * 32 + quad * 8) ^ xl)];
      acc = mfma16(a, b, acc);
    }
#pragma unroll
    for (int r = 0; r < 4; ++r) {
      int row = w * 16 + quad * 4 + r;
      sL[row * 16 + ll] = acc[r] + ((ll < 10) ? bo2[ll] : 0.f);
    }
  }
  __syncthreads();
  if (tid < 64) {
    float m = -1e30f;
#pragma unroll
    for (int c = 0; c < 10; ++c) m = fmaxf(m, sL[tid * 16 + c]);
    float s = 0.f;
#pragma unroll
    for (int c = 0; c < 10; ++c) s += expf(sL[tid * 16 + c] - m);
    float ls = logf(s) + m;
#pragma unroll
    for (int c = 0; c < 10; ++c) outp[(b0 + tid) * 10 + c] = sL[tid * 16 + c] - ls;
  }
}

extern "C" void kernel_launch(void* const* d_in, const int* in_sizes, int n_in,
                              void* d_out, int out_size, void* d_ws, size_t ws_size,
                              hipStream_t stream) {
  const float* tabs = (const float*)d_in[0];
  const float* qst  = (const float*)d_in[1];
  const float* Wi1 = (const float*)d_in[2];  const float* bi1 = (const float*)d_in[3];
  const float* Wi2 = (const float*)d_in[4];  const float* bi2 = (const float*)d_in[5];
  const float* Wi3 = (const float*)d_in[6];  const float* bi3 = (const float*)d_in[7];
  const float* Wg1 = (const float*)d_in[8];  const float* bg1 = (const float*)d_in[9];
  const float* Wg2 = (const float*)d_in[10]; const float* bg2 = (const float*)d_in[11];
  const float* Wg3 = (const float*)d_in[12]; const float* bg3 = (const float*)d_in[13];
  const float* Wg4 = (const float*)d_in[14]; const float* bg4 = (const float*)d_in[15];
  const float* Wf  = (const float*)d_in[16]; const float* bf_ = (const float*)d_in[17];
  const float* Wo1 = (const float*)d_in[18]; const float* bo1 = (const float*)d_in[19];
  const float* Wo2 = (const float*)d_in[20]; const float* bo2 = (const float*)d_in[21];
  float* outp = (float*)d_out;
  (void)in_sizes; (void)n_in; (void)out_size; (void)ws_size;

  char* ws = (char*)d_ws;
  size_t off = 0;
  auto alloc = [&](size_t bytes) { void* p = ws + off; off += (bytes + 255) & ~(size_t)255; return p; };
  const size_t BN = 16384ull * 6;
  short* u_g = (short*)alloc(BN * 256 * 2);
  short* v_g = (short*)alloc(BN * 256 * 2);
  float* qb  = (float*)alloc(16384ull * 256 * 4);
  float* g_g = (float*)alloc(16384ull * 256 * 4);
  short* Wi1p = (short*)alloc(16 * 1 * 64 * 8 * 2);
  short* Wi2p = (short*)alloc(8 * 8 * 64 * 8 * 2);
  short* Wi3p = (short*)alloc(8 * 4 * 64 * 8 * 2);
  short* Wap  = (short*)alloc(16 * 4 * 64 * 8 * 2);
  short* Wbp  = (short*)alloc(16 * 4 * 64 * 8 * 2);
  short* Wg2p = (short*)alloc(16 * 8 * 64 * 8 * 2);
  short* Wg3p = (short*)alloc(16 * 8 * 64 * 8 * 2);
  short* Wg4p = (short*)alloc(16 * 8 * 64 * 8 * 2);
  short* Wfp  = (short*)alloc(16 * 8 * 64 * 8 * 2);
  short* Wo1p = (short*)alloc(16 * 8 * 64 * 8 * 2);
  short* Wo2p = (short*)alloc(1 * 8 * 64 * 8 * 2);

  PPArgs pa;
  int tb = 0, nd = 0;
  auto add = [&](const float* src, short* dst, int Ks, int Ns, int KT, int NT) {
    pa.d[nd++] = PPDesc{src, dst, Ks, Ns, KT, NT, tb};
    tb += KT * NT;
  };
  add(Wi1, Wi1p, 10, 256, 1, 16);
  add(Wi2, Wi2p, 256, 128, 8, 8);
  add(Wi3, Wi3p, 128, 100, 4, 8);
  add(Wg1,             Wap, 100, 256, 4, 16);
  add(Wg1 + 100 * 256, Wbp, 100, 256, 4, 16);
  add(Wg2, Wg2p, 256, 256, 8, 16);
  add(Wg3, Wg3p, 256, 256, 8, 16);
  add(Wg4, Wg4p, 256, 256, 8, 16);
  add(Wf,  Wfp,  256, 256, 8, 16);
  add(Wo1, Wo1p, 256, 256, 8, 16);
  add(Wo2, Wo2p, 256, 10, 8, 1);
  pa.n_desc = nd;
  pa.total_tiles = tb;
  prepack_all<<<(tb * 64 + 255) / 256, 256, 0, stream>>>(pa);

  qb_kernel<<<512, 256, 0, stream>>>(qst, Wg1, bg1, qb);
  enc_kernel<<<1536, 256, 0, stream>>>(tabs, bi1, bi2, bi3, Wi1p, Wi2p, Wi3p, Wap, Wbp, u_g, v_g);
  pair_kernel<<<8192, 512, 0, stream>>>(u_g, v_g, qb, Wg2p, Wg3p, Wg4p, bg2, bg3, bg4, g_g);
  head_kernel<<<256, 256, 0, stream>>>(g_g, Wfp, bf_, Wo1p, bo1, Wo2p, bo2, outp);
}

// Round 5
// 452.431 us; speedup vs baseline: 2.0434x; 1.2225x over previous
//
#include <hip/hip_runtime.h>
#include <hip/hip_bf16.h>
#include <stdint.h>

// ---------- types ----------
typedef __attribute__((ext_vector_type(8))) __bf16 bf16x8;
typedef __attribute__((ext_vector_type(8))) short short8v;
typedef __attribute__((ext_vector_type(4))) short short4v;
typedef __attribute__((ext_vector_type(4))) float f32x4;

__device__ __forceinline__ float bf2f(short u) {
  return __builtin_bit_cast(float, (uint32_t)((uint32_t)(uint16_t)u << 16));
}
__device__ __forceinline__ short f2bf(float f) {
  uint32_t x = __builtin_bit_cast(uint32_t, f);
  x += 0x7FFFu + ((x >> 16) & 1u);
  return (short)(x >> 16);
}
__device__ __forceinline__ f32x4 mfma16(short8v a, short8v b, f32x4 c) {
  return __builtin_amdgcn_mfma_f32_16x16x32_bf16(
      __builtin_bit_cast(bf16x8, a), __builtin_bit_cast(bf16x8, b), c, 0, 0, 0);
}
// XOR-swizzled LDS address (shorts), stride 256/128 shorts, 16B-chunk swizzle.
__device__ __forceinline__ int swz256(int row, int col) {
  return row * 256 + (col ^ ((row & 7) << 3));
}
__device__ __forceinline__ int swz128(int row, int col) {
  return row * 128 + (col ^ ((row & 7) << 3));
}

// ---------- merged prepack: all 11 weights in ONE launch ----------
// dst layout per weight: [nt][kt][lane][8 bf16]; B[k=kt*32+(lane>>4)*8+j][n=nt*16+(lane&15)]
struct PPDesc { const float* src; short* dst; int Ks, Ns, KT, NT, tile_base; };
struct PPArgs { PPDesc d[11]; int n_desc; int total_tiles; };

__global__ void prepack_all(PPArgs args) {
  int idx = blockIdx.x * 256 + threadIdx.x;
  int tile = idx >> 6;
  if (tile >= args.total_tiles) return;
  int lane = idx & 63;
  int e = 0;
  while (e + 1 < args.n_desc && args.d[e + 1].tile_base <= tile) ++e;
  const PPDesc D = args.d[e];
  int t = tile - D.tile_base;
  int kt = t % D.KT, nt = t / D.KT;
  int n = nt * 16 + (lane & 15);
  int kbase = kt * 32 + ((lane >> 4) * 8);
  short8v o;
#pragma unroll
  for (int j = 0; j < 8; ++j) {
    int k = kbase + j;
    o[j] = f2bf((k < D.Ks && n < D.Ns) ? D.src[k * D.Ns + n] : 0.f);
  }
  *(short8v*)&D.dst[((size_t)t * 64 + lane) * 8] = o;
}

// ---------- qb[b,c] = qst[b] @ Wg1[200:211] + bg1 (32 batches/block) ----------
__global__ void qb_kernel(const float* __restrict__ qst, const float* __restrict__ Wg1,
                          const float* __restrict__ bg1, float* __restrict__ qb) {
  int c = threadIdx.x;
  int b0 = blockIdx.x * 32;
  float wcol[11];
#pragma unroll
  for (int k = 0; k < 11; ++k) wcol[k] = Wg1[(200 + k) * 256 + c];
  float bias = bg1[c];
#pragma unroll 1
  for (int bb = 0; bb < 32; ++bb) {
    int b = b0 + bb;
    float acc = bias;
#pragma unroll
    for (int k = 0; k < 11; ++k) acc += qst[b * 11 + k] * wcol[k];
    qb[b * 256 + c] = acc;
  }
}

// ---------- encoder: tabs[64 rows x 10] -> x -> u,v (bf16, [obj][256]) ----------
__launch_bounds__(256, 3)
__global__ void enc_kernel(const float* __restrict__ tabs,
    const float* __restrict__ bi1, const float* __restrict__ bi2, const float* __restrict__ bi3,
    const short* __restrict__ Wi1p, const short* __restrict__ Wi2p, const short* __restrict__ Wi3p,
    const short* __restrict__ Wap, const short* __restrict__ Wbp,
    short* __restrict__ u_g, short* __restrict__ v_g) {
  __shared__ __align__(16) short sIn[64 * 32];   // K padded 10->32
  __shared__ __align__(16) short sH1[64 * 256];  // swizzled; sX aliases this after L2
  __shared__ __align__(16) short sH2[64 * 128];  // swizzled
  short* sX = sH1;                               // reuse (stride 128, swizzled)
  const int tid = threadIdx.x;
  const int lane = tid & 63, w = tid >> 6, quad = lane >> 4, ll = lane & 15;
  const int xl = (ll & 7) << 3;
  const int obj0 = blockIdx.x * 64;

  for (int idx = tid; idx < 64 * 32; idx += 256) {
    int r = idx >> 5, k = idx & 31;
    float v = (k < 10) ? tabs[(obj0 + r) * 10 + k] : 0.f;
    sIn[idx] = f2bf(v);
  }
  __syncthreads();

  // L1: relu(in @ Wi1 + bi1)  K=32(pad), N=256
  {
    f32x4 acc[4][4] = {};
    short8v a[4];
#pragma unroll
    for (int mt = 0; mt < 4; ++mt)
      a[mt] = *(const short8v*)&sIn[(mt * 16 + ll) * 32 + quad * 8];
#pragma unroll
    for (int ni = 0; ni < 4; ++ni) {
      short8v b = *(const short8v*)&Wi1p[((w * 4 + ni) * 64 + lane) * 8];
#pragma unroll
      for (int mt = 0; mt < 4; ++mt) acc[mt][ni] = mfma16(a[mt], b, acc[mt][ni]);
    }
#pragma unroll
    for (int ni = 0; ni < 4; ++ni) {
      int col = (w * 4 + ni) * 16 + ll;
      float bias = bi1[col];
#pragma unroll
      for (int mt = 0; mt < 4; ++mt)
#pragma unroll
        for (int r = 0; r < 4; ++r) {
          int row = mt * 16 + quad * 4 + r;
          sH1[swz256(row, col)] = f2bf(fmaxf(acc[mt][ni][r] + bias, 0.f));
        }
    }
  }
  __syncthreads();

  // L2: relu(h1 @ Wi2 + bi2)  K=256, N=128
  {
    f32x4 acc[4][2] = {};
#pragma unroll 1
    for (int kt = 0; kt < 8; ++kt) {
      short8v b[2];
#pragma unroll
      for (int ni = 0; ni < 2; ++ni)
        b[ni] = *(const short8v*)&Wi2p[(((w * 2 + ni) * 8 + kt) * 64 + lane) * 8];
#pragma unroll
      for (int mt = 0; mt < 4; ++mt) {
        short8v a = *(const short8v*)&sH1[(mt * 16 + ll) * 256 + ((kt * 32 + quad * 8) ^ xl)];
#pragma unroll
        for (int ni = 0; ni < 2; ++ni) acc[mt][ni] = mfma16(a, b[ni], acc[mt][ni]);
      }
    }
    __syncthreads();   // sH1 reads done (sX will overwrite it after L3)
#pragma unroll
    for (int ni = 0; ni < 2; ++ni) {
      int col = (w * 2 + ni) * 16 + ll;
      float bias = bi2[col];
#pragma unroll
      for (int mt = 0; mt < 4; ++mt)
#pragma unroll
        for (int r = 0; r < 4; ++r) {
          int row = mt * 16 + quad * 4 + r;
          sH2[swz128(row, col)] = f2bf(fmaxf(acc[mt][ni][r] + bias, 0.f));
        }
    }
  }
  __syncthreads();

  // L3: x = h2 @ Wi3 + bi3 (NO relu)  K=128, N=128(pad, cols>=100 zero) -> sX (aliases sH1)
  {
    f32x4 acc[4][2] = {};
#pragma unroll 1
    for (int kt = 0; kt < 4; ++kt) {
      short8v b[2];
#pragma unroll
      for (int ni = 0; ni < 2; ++ni)
        b[ni] = *(const short8v*)&Wi3p[(((w * 2 + ni) * 4 + kt) * 64 + lane) * 8];
#pragma unroll
      for (int mt = 0; mt < 4; ++mt) {
        short8v a = *(const short8v*)&sH2[(mt * 16 + ll) * 128 + ((kt * 32 + quad * 8) ^ xl)];
#pragma unroll
        for (int ni = 0; ni < 2; ++ni) acc[mt][ni] = mfma16(a, b[ni], acc[mt][ni]);
      }
    }
#pragma unroll
    for (int ni = 0; ni < 2; ++ni) {
      int col = (w * 2 + ni) * 16 + ll;
      float bias = (col < 100) ? bi3[col] : 0.f;
#pragma unroll
      for (int mt = 0; mt < 4; ++mt)
#pragma unroll
        for (int r = 0; r < 4; ++r) {
          int row = mt * 16 + quad * 4 + r;
          float vv = (col < 100) ? (acc[mt][ni][r] + bias) : 0.f;
          sX[swz128(row, col)] = f2bf(vv);
        }
    }
  }
  __syncthreads();

  // L4: u = x @ Wa ; v = x @ Wb   K=128, N=256 each
#pragma unroll 1
  for (int pass = 0; pass < 2; ++pass) {
    const short* Wp = pass ? Wbp : Wap;
    short* outg = pass ? v_g : u_g;
    f32x4 acc[4][4] = {};
#pragma unroll 1
    for (int kt = 0; kt < 4; ++kt) {
      short8v b[4];
#pragma unroll
      for (int ni = 0; ni < 4; ++ni)
        b[ni] = *(const short8v*)&Wp[(((w * 4 + ni) * 4 + kt) * 64 + lane) * 8];
#pragma unroll
      for (int mt = 0; mt < 4; ++mt) {
        short8v a = *(const short8v*)&sX[(mt * 16 + ll) * 128 + ((kt * 32 + quad * 8) ^ xl)];
#pragma unroll
        for (int ni = 0; ni < 4; ++ni) acc[mt][ni] = mfma16(a, b[ni], acc[mt][ni]);
      }
    }
#pragma unroll
    for (int ni = 0; ni < 4; ++ni) {
      int col = (w * 4 + ni) * 16 + ll;
#pragma unroll
      for (int mt = 0; mt < 4; ++mt)
#pragma unroll
        for (int r = 0; r < 4; ++r)
          outg[(obj0 + mt * 16 + quad * 4 + r) * 256 + col] = f2bf(acc[mt][ni][r]);
    }
  }
}

// ---------- pair MLP: 512 threads (8 waves), 2 batches/block, 72 rows (pad->80) ----------
// (512,4): 128 regs/wave budget; acc[5][2]=40 AGPR + ~50 VGPR fits with headroom -> NO
// spill (round-4 lesson: (512,6) capped at 85 and spilled ~600 MB to scratch).
// 2 blocks/CU (16 waves). Pool: wave-private cols -> shfl reduce -> direct global store.
__launch_bounds__(512, 4)
__global__ void pair_kernel(const short* __restrict__ u_g, const short* __restrict__ v_g,
    const float* __restrict__ qbp,
    const short* __restrict__ Wg2p, const short* __restrict__ Wg3p, const short* __restrict__ Wg4p,
    const float* __restrict__ bg2, const float* __restrict__ bg3, const float* __restrict__ bg4,
    float* __restrict__ g_g) {
  __shared__ __align__(16) short sH[80 * 256];   // 40,960 B, swizzled
  const int tid = threadIdx.x;
  const int lane = tid & 63, w = tid >> 6, quad = lane >> 4, ll = lane & 15;
  const int xl = (ll & 7) << 3;
  const int b0 = blockIdx.x * 2;

  // zero pad rows 72..79 (2048 shorts)
  if (tid < 256) *(short8v*)&sH[72 * 256 + tid * 8] = short8v{0, 0, 0, 0, 0, 0, 0, 0};

  // h1 = relu(u[j] + v[i] + qb): one 16B chunk (8 cols of one row) per thread.
  // row = bb*36 + i*6 + j; 72 rows x 32 chunks = 2304 chunks.
#pragma unroll 1
  for (int it = 0; it < 5; ++it) {
    int vi = it * 512 + tid;
    if (vi < 2304) {
      int row = vi >> 5, c8 = (vi & 31) * 8;
      int bb = row / 36, p = row - bb * 36;
      int i2 = p / 6, j2 = p - i2 * 6;
      short8v u8 = *(const short8v*)&u_g[((b0 + bb) * 6 + j2) * 256 + c8];
      short8v v8 = *(const short8v*)&v_g[((b0 + bb) * 6 + i2) * 256 + c8];
      f32x4 qa = *(const f32x4*)&qbp[(b0 + bb) * 256 + c8];
      f32x4 qc = *(const f32x4*)&qbp[(b0 + bb) * 256 + c8 + 4];
      short8v o;
#pragma unroll
      for (int e = 0; e < 4; ++e)
        o[e] = f2bf(fmaxf(bf2f(u8[e]) + bf2f(v8[e]) + qa[e], 0.f));
#pragma unroll
      for (int e = 0; e < 4; ++e)
        o[4 + e] = f2bf(fmaxf(bf2f(u8[4 + e]) + bf2f(v8[4 + e]) + qc[e], 0.f));
      *(short8v*)&sH[row * 256 + (c8 ^ ((row & 7) << 3))] = o;
    }
  }
  __syncthreads();

#pragma unroll 1
  for (int L = 0; L < 3; ++L) {
    const short* __restrict__ Wp = (L == 0) ? Wg2p : (L == 1) ? Wg3p : Wg4p;
    const float* __restrict__ bp = (L == 0) ? bg2 : (L == 1) ? bg3 : bg4;
    f32x4 acc[5][2] = {};
#pragma unroll 1
    for (int kt = 0; kt < 8; ++kt) {
      short8v b[2];
#pragma unroll
      for (int ni = 0; ni < 2; ++ni)
        b[ni] = *(const short8v*)&Wp[(((w * 2 + ni) * 8 + kt) * 64 + lane) * 8];
#pragma unroll
      for (int mt = 0; mt < 5; ++mt) {
        short8v a = *(const short8v*)&sH[(mt * 16 + ll) * 256 + ((kt * 32 + quad * 8) ^ xl)];
#pragma unroll
        for (int ni = 0; ni < 2; ++ni) acc[mt][ni] = mfma16(a, b[ni], acc[mt][ni]);
      }
    }
    __syncthreads();  // all reads of sH done before in-place overwrite
    if (L < 2) {
#pragma unroll
      for (int ni = 0; ni < 2; ++ni) {
        int col = (w * 2 + ni) * 16 + ll;
        float bias = bp[col];
#pragma unroll
        for (int mt = 0; mt < 5; ++mt)
#pragma unroll
          for (int r = 0; r < 4; ++r) {
            int row = mt * 16 + quad * 4 + r;
            sH[swz256(row, col)] = f2bf(fmaxf(acc[mt][ni][r] + bias, 0.f));
          }
      }
      __syncthreads();
    } else {
      // g4: relu + sum-pool, atomic-free. Lane accumulates its rows per batch,
      // cross-quad shfl reduce, quad 0 stores straight to global (cols wave-private).
#pragma unroll
      for (int ni = 0; ni < 2; ++ni) {
        int col = (w * 2 + ni) * 16 + ll;
        float bias = bp[col];
        float s0 = 0.f, s1 = 0.f;
#pragma unroll
        for (int mt = 0; mt < 5; ++mt) {
          int rbase = mt * 16 + quad * 4;
          float t = 0.f;
#pragma unroll
          for (int r = 0; r < 4; ++r) t += fmaxf(acc[mt][ni][r] + bias, 0.f);
          if (rbase < 36) s0 += t;
          else if (rbase < 72) s1 += t;
        }
        s0 += __shfl_xor(s0, 16, 64); s0 += __shfl_xor(s0, 32, 64);
        s1 += __shfl_xor(s1, 16, 64); s1 += __shfl_xor(s1, 32, 64);
        if (quad == 0) {
          g_g[(size_t)(b0 + 0) * 256 + col] = s0;
          g_g[(size_t)(b0 + 1) * 256 + col] = s1;
        }
      }
    }
  }
}

// ---------- head helper: 64x256 @ 256x256 + bias + relu, LDS->LDS (swizzled) ----------
__device__ __forceinline__ void gemm64x256(const short* sInp, short* sOut,
    const short* __restrict__ Wp, const float* __restrict__ bias,
    int w, int lane, int quad, int ll, int xl) {
  f32x4 acc[4][4] = {};
#pragma unroll 1
  for (int kt = 0; kt < 8; ++kt) {
    short8v b[4];
#pragma unroll
    for (int ni = 0; ni < 4; ++ni)
      b[ni] = *(const short8v*)&Wp[(((w * 4 + ni) * 8 + kt) * 64 + lane) * 8];
#pragma unroll
    for (int mt = 0; mt < 4; ++mt) {
      short8v a = *(const short8v*)&sInp[(mt * 16 + ll) * 256 + ((kt * 32 + quad * 8) ^ xl)];
#pragma unroll
      for (int ni = 0; ni < 4; ++ni) acc[mt][ni] = mfma16(a, b[ni], acc[mt][ni]);
    }
  }
#pragma unroll
  for (int ni = 0; ni < 4; ++ni) {
    int col = (w * 4 + ni) * 16 + ll;
    float bv = bias[col];
#pragma unroll
    for (int mt = 0; mt < 4; ++mt)
#pragma unroll
      for (int r = 0; r < 4; ++r) {
        int row = mt * 16 + quad * 4 + r;
        sOut[swz256(row, col)] = f2bf(fmaxf(acc[mt][ni][r] + bv, 0.f));
      }
  }
}

// ---------- head: g -> f -> o -> logits -> log_softmax ----------
__launch_bounds__(256, 2)
__global__ void head_kernel(const float* __restrict__ g_g,
    const short* __restrict__ Wfp, const float* __restrict__ bf_,
    const short* __restrict__ Wo1p, const float* __restrict__ bo1,
    const short* __restrict__ Wo2p, const float* __restrict__ bo2,
    float* __restrict__ outp) {
  __shared__ __align__(16) short sA[64 * 256];
  __shared__ __align__(16) short sB[64 * 256];
  __shared__ float sL[64 * 16];
  const int tid = threadIdx.x;
  const int lane = tid & 63, w = tid >> 6, quad = lane >> 4, ll = lane & 15;
  const int xl = (ll & 7) << 3;
  const int b0 = blockIdx.x * 64;

#pragma unroll 1
  for (int it = 0; it < 16; ++it) {
    int vi = it * 256 + tid;
    int row = vi >> 6, c4 = (vi & 63) * 4;
    f32x4 gv = *(const f32x4*)&g_g[(b0 + row) * 256 + c4];
    short4v o;
#pragma unroll
    for (int e = 0; e < 4; ++e) o[e] = f2bf(gv[e]);
    *(short4v*)&sA[row * 256 + (c4 ^ ((row & 7) << 3))] = o;
  }
  __syncthreads();
  gemm64x256(sA, sB, Wfp, bf_, w, lane, quad, ll, xl);
  __syncthreads();
  gemm64x256(sB, sA, Wo1p, bo1, w, lane, quad, ll, xl);
  __syncthreads();
  {
    f32x4 acc = {};
#pragma unroll 1
    for (int kt = 0; kt < 8; ++kt) {
      short8v b = *(const short8v*)&Wo2p[(kt * 64 + lane) * 8];
      short8v a = *(const short8v*)&sA[(w * 16 + ll) * 256 + ((kt * 32 + quad * 8) ^ xl)];
      acc = mfma16(a, b, acc);
    }
#pragma unroll
    for (int r = 0; r < 4; ++r) {
      int row = w * 16 + quad * 4 + r;
      sL[row * 16 + ll] = acc[r] + ((ll < 10) ? bo2[ll] : 0.f);
    }
  }
  __syncthreads();
  if (tid < 64) {
    float m = -1e30f;
#pragma unroll
    for (int c = 0; c < 10; ++c) m = fmaxf(m, sL[tid * 16 + c]);
    float s = 0.f;
#pragma unroll
    for (int c = 0; c < 10; ++c) s += expf(sL[tid * 16 + c] - m);
    float ls = logf(s) + m;
#pragma unroll
    for (int c = 0; c < 10; ++c) outp[(b0 + tid) * 10 + c] = sL[tid * 16 + c] - ls;
  }
}

extern "C" void kernel_launch(void* const* d_in, const int* in_sizes, int n_in,
                              void* d_out, int out_size, void* d_ws, size_t ws_size,
                              hipStream_t stream) {
  const float* tabs = (const float*)d_in[0];
  const float* qst  = (const float*)d_in[1];
  const float* Wi1 = (const float*)d_in[2];  const float* bi1 = (const float*)d_in[3];
  const float* Wi2 = (const float*)d_in[4];  const float* bi2 = (const float*)d_in[5];
  const float* Wi3 = (const float*)d_in[6];  const float* bi3 = (const float*)d_in[7];
  const float* Wg1 = (const float*)d_in[8];  const float* bg1 = (const float*)d_in[9];
  const float* Wg2 = (const float*)d_in[10]; const float* bg2 = (const float*)d_in[11];
  const float* Wg3 = (const float*)d_in[12]; const float* bg3 = (const float*)d_in[13];
  const float* Wg4 = (const float*)d_in[14]; const float* bg4 = (const float*)d_in[15];
  const float* Wf  = (const float*)d_in[16]; const float* bf_ = (const float*)d_in[17];
  const float* Wo1 = (const float*)d_in[18]; const float* bo1 = (const float*)d_in[19];
  const float* Wo2 = (const float*)d_in[20]; const float* bo2 = (const float*)d_in[21];
  float* outp = (float*)d_out;
  (void)in_sizes; (void)n_in; (void)out_size; (void)ws_size;

  char* ws = (char*)d_ws;
  size_t off = 0;
  auto alloc = [&](size_t bytes) { void* p = ws + off; off += (bytes + 255) & ~(size_t)255; return p; };
  const size_t BN = 16384ull * 6;
  short* u_g = (short*)alloc(BN * 256 * 2);
  short* v_g = (short*)alloc(BN * 256 * 2);
  float* qb  = (float*)alloc(16384ull * 256 * 4);
  float* g_g = (float*)alloc(16384ull * 256 * 4);
  short* Wi1p = (short*)alloc(16 * 1 * 64 * 8 * 2);
  short* Wi2p = (short*)alloc(8 * 8 * 64 * 8 * 2);
  short* Wi3p = (short*)alloc(8 * 4 * 64 * 8 * 2);
  short* Wap  = (short*)alloc(16 * 4 * 64 * 8 * 2);
  short* Wbp  = (short*)alloc(16 * 4 * 64 * 8 * 2);
  short* Wg2p = (short*)alloc(16 * 8 * 64 * 8 * 2);
  short* Wg3p = (short*)alloc(16 * 8 * 64 * 8 * 2);
  short* Wg4p = (short*)alloc(16 * 8 * 64 * 8 * 2);
  short* Wfp  = (short*)alloc(16 * 8 * 64 * 8 * 2);
  short* Wo1p = (short*)alloc(16 * 8 * 64 * 8 * 2);
  short* Wo2p = (short*)alloc(1 * 8 * 64 * 8 * 2);

  PPArgs pa;
  int tb = 0, nd = 0;
  auto add = [&](const float* src, short* dst, int Ks, int Ns, int KT, int NT) {
    pa.d[nd++] = PPDesc{src, dst, Ks, Ns, KT, NT, tb};
    tb += KT * NT;
  };
  add(Wi1, Wi1p, 10, 256, 1, 16);
  add(Wi2, Wi2p, 256, 128, 8, 8);
  add(Wi3, Wi3p, 128, 100, 4, 8);
  add(Wg1,             Wap, 100, 256, 4, 16);
  add(Wg1 + 100 * 256, Wbp, 100, 256, 4, 16);
  add(Wg2, Wg2p, 256, 256, 8, 16);
  add(Wg3, Wg3p, 256, 256, 8, 16);
  add(Wg4, Wg4p, 256, 256, 8, 16);
  add(Wf,  Wfp,  256, 256, 8, 16);
  add(Wo1, Wo1p, 256, 256, 8, 16);
  add(Wo2, Wo2p, 256, 10, 8, 1);
  pa.n_desc = nd;
  pa.total_tiles = tb;
  prepack_all<<<(tb * 64 + 255) / 256, 256, 0, stream>>>(pa);

  qb_kernel<<<512, 256, 0, stream>>>(qst, Wg1, bg1, qb);
  enc_kernel<<<1536, 256, 0, stream>>>(tabs, bi1, bi2, bi3, Wi1p, Wi2p, Wi3p, Wap, Wbp, u_g, v_g);
  pair_kernel<<<8192, 512, 0, stream>>>(u_g, v_g, qb, Wg2p, Wg3p, Wg4p, bg2, bg3, bg4, g_g);
  head_kernel<<<256, 256, 0, stream>>>(g_g, Wfp, bf_, Wo1p, bo1, Wo2p, bo2, outp);
}